// Round 5
// baseline (405.219 us; speedup 1.0000x reference)
//
#include <hip/hip_runtime.h>
#include <hip/hip_bf16.h>

// Dims (fixed for this problem)
#define BB 2
#define LL 1024
#define DMODEL 1024
#define DINNER 2048
#define DSTATE 16
#define DCONV 4
#define MM (BB * LL)          // 2048
#define N_XZ 4096
#define N_SSM 2080
#define N_SSM_PAD 2176        // 34 * 64
#define CCH 32                // chunks over L
#define LCH 32                // chunk length (CCH*LCH == LL)

typedef __hip_bfloat16 bf16;
typedef short bf16x8 __attribute__((ext_vector_type(8)));
typedef float f32x4 __attribute__((ext_vector_type(4)));

// ---------------- async global -> LDS, 16B per lane ----------------
__device__ __forceinline__ void load16_lds(const bf16* g, bf16* l) {
    __builtin_amdgcn_global_load_lds(
        (const __attribute__((address_space(1))) void*)g,
        (__attribute__((address_space(3))) void*)l,
        16, 0, 0);
}

template<int SWZ>
__device__ __forceinline__ void remap(int id, int NX, int& bx, int& by) {
    if (SWZ >= 0) {   // bind XCD (id&7) to a contiguous 2^SWZ range of n-tiles
        int xcd = id & 7, slot = id >> 3;
        bx = (xcd << SWZ) + (slot & ((1 << SWZ) - 1));
        by = slot >> SWZ;
    } else { bx = id % NX; by = id / NX; }
}

// ---------------- fused prep: 3 weight transposes + W2 cvt + BC-slice transpose + x cvt
__global__ __launch_bounds__(256) void prep_kernel(
    const float* __restrict__ x, bf16* __restrict__ xbf,
    const float* __restrict__ w1, bf16* __restrict__ o1,
    const float* __restrict__ w3, bf16* __restrict__ o3,
    const float* __restrict__ w4, bf16* __restrict__ o4,
    const float* __restrict__ w2, bf16* __restrict__ w2bf,
    bf16* __restrict__ w2bc)
{
    int bid = blockIdx.x;
    if (bid >= 14464) {                 // x cvt: 2048 blocks x 1024 elems
        bid -= 14464;
        int i = (bid * 256 + threadIdx.x) * 4;
        float4 v = *(const float4*)(x + i);
        xbf[i + 0] = __float2bfloat16(v.x);
        xbf[i + 1] = __float2bfloat16(v.y);
        xbf[i + 2] = __float2bfloat16(v.z);
        xbf[i + 3] = __float2bfloat16(v.w);
        return;
    }
    if (bid >= 10240 && bid < 14400) {  // w2 cvt: 2048*2080 f32 -> bf16, 4160 blocks
        bid -= 10240;
        int i = (bid * 256 + threadIdx.x) * 4;
        float4 v = *(const float4*)(w2 + i);
        w2bf[i + 0] = __float2bfloat16(v.x);
        w2bf[i + 1] = __float2bfloat16(v.y);
        w2bf[i + 2] = __float2bfloat16(v.z);
        w2bf[i + 3] = __float2bfloat16(v.w);
        return;
    }
    const float* src; bf16* dst; int K, N, tn, tk, srcld;
    if (bid < 4096)        { src = w1; dst = o1; K = 1024; N = 4096; tn = bid & 127; tk = bid >> 7; srcld = N; }
    else if (bid < 8192)   { bid -= 4096; src = w3; dst = o3; K = 2048; N = 2048; tn = bid & 63; tk = bid >> 6; srcld = N; }
    else if (bid < 10240)  { bid -= 8192; src = w4; dst = o4; K = 2048; N = 1024; tn = bid & 31; tk = bid >> 5; srcld = N; }
    else                   { bid -= 14400; src = w2; dst = w2bc; K = 2048; N = 32; tn = 0; tk = bid; srcld = N_SSM; }
    __shared__ float tile[32][33];
    const int nb = tn * 32, kb = tk * 32;
    const int tx = threadIdx.x & 31, ty = threadIdx.x >> 5;
    #pragma unroll
    for (int i = 0; i < 32; i += 8) {
        int k = kb + ty + i, n = nb + tx;
        tile[ty + i][tx] = (k < K && n < N) ? src[(size_t)k * srcld + n] : 0.f;
    }
    __syncthreads();
    #pragma unroll
    for (int i = 0; i < 32; i += 8) {
        int n = nb + ty + i, k = kb + tx;
        if (n < N && k < K) dst[(size_t)n * K + k] = __float2bfloat16(tile[tx][ty + i]);
    }
}

// ================= 8-PHASE 256x256 GEMM (T2+T3+T4+T5 port) =================
// 512 thr = 8 waves (2M x 4N); wave owns 128x64 (acc[8][4]); BK=64.
// LDS 128 KB: buf{0,1} x (A[256][64] + B[256][64]) bf16, chunk-XOR swizzled
// (session-verified: stage chunk (l&7)^(row&7), read chunk (ks*4+kq)^(lm&7);
//  SQ_LDS_BANK_CONFLICT == 0 on HW).
// Iteration = 2 K-tiles = 8 phases; per phase: {ds-reads, 1 half-tile stage,
// [vmcnt], barrier, MFMA quadrant (setprio), barrier}. Counted vmcnt(4) at
// p3/p7 only (derived: guarantees all halves of the next-consumed K-tile
// landed; 2 stages stay in flight). Stage slots (iter i, t=2i):
//   p0:Ah0(t+1) p1:Ah1(t+1) -> buf1 (A(t-1) freed at p6(i-1))
//   p2:Bh0(t+2) p3:Bh1(t+2) -> buf0 (B(t) freed at p1)
//   p4:Ah0(t+2) p5:Ah1(t+2) -> buf0 (A(t) freed at p2)
//   p6:Bh0(t+3) p7:Bh1(t+3) -> buf1 (B(t+1) freed at p5)
// EPI: 0 = bf16 store; 2 = f32 atomicAdd (split-K partials)
template<int EPI>
__device__ __forceinline__ void gemm8_body(
    bf16* lds, int bx, int by,
    const bf16* __restrict__ A, int lda,
    const bf16* __restrict__ Wt, int ldw,
    float* __restrict__ Cf, bf16* __restrict__ Cb, int ldc,
    int N, int K, int kbeg, int Kc)
{
    const int tid = threadIdx.x;
    const int wave = tid >> 6, lane = tid & 63;
    const int wr = wave >> 2, wc = wave & 3;      // 2x4 wave grid
    const int lm = lane & 15, kq = lane >> 4;
    const int fsw = lm & 7;
    const int m0 = by * 256, n0 = bx * 256;
    const int NT = Kc / 64, NI = NT / 2;          // NT even, NI >= 2

    // staging source: lane covers row (lane>>3) of its 8-row group,
    // chunk (lane&7)^(lane>>3); wave w covers rows w*16 + g*8 (g=0,1) per half.
    const int sr = lane >> 3;
    const int sc8 = ((lane & 7) ^ sr) * 8;
    const bf16* gA = A  + (size_t)(m0 + wave * 16 + sr) * lda + sc8;
    const bf16* gB = Wt + (size_t)(n0 + wave * 16 + sr) * ldw + sc8;

    auto stageA = [&](int buf, int h, int t) {
        const size_t k0 = (size_t)kbeg + (size_t)t * 64;
        #pragma unroll
        for (int g = 0; g < 2; ++g)
            load16_lds(gA + (size_t)(h * 128 + g * 8) * lda + k0,
                       lds + buf * 32768 + (h * 128 + wave * 16 + g * 8) * 64);
    };
    auto stageB = [&](int buf, int h, int t) {
        const size_t k0 = (size_t)kbeg + (size_t)t * 64;
        #pragma unroll
        for (int g = 0; g < 2; ++g)
            load16_lds(gB + (size_t)(h * 128 + g * 8) * ldw + k0,
                       lds + buf * 32768 + 16384 + (h * 128 + wave * 16 + g * 8) * 64);
    };

    f32x4 acc[8][4] = {};
    bf16x8 af[4][2], bfr[4][2];

    auto readAf = [&](int buf, int qm) {
        const bf16* Ab = lds + buf * 32768;
        #pragma unroll
        for (int m = 0; m < 4; ++m)
            #pragma unroll
            for (int ks = 0; ks < 2; ++ks)
                af[m][ks] = *(const bf16x8*)(Ab + (wr * 128 + (qm * 4 + m) * 16 + lm) * 64
                                                + (((ks * 4 + kq) ^ fsw) * 8));
    };
    auto readBf = [&](int buf, int qn) {
        const bf16* Bb = lds + buf * 32768 + 16384;
        #pragma unroll
        for (int n = 0; n < 2; ++n)
            #pragma unroll
            for (int ks = 0; ks < 2; ++ks)
                bfr[qn * 2 + n][ks] = *(const bf16x8*)(Bb + (wc * 64 + (qn * 2 + n) * 16 + lm) * 64
                                                          + (((ks * 4 + kq) ^ fsw) * 8));
    };
    auto mfmaQ = [&](int qm, int qn) {
        __builtin_amdgcn_s_setprio(1);
        #pragma unroll
        for (int ks = 0; ks < 2; ++ks)
            #pragma unroll
            for (int m = 0; m < 4; ++m)
                #pragma unroll
                for (int n = 0; n < 2; ++n)
                    acc[qm * 4 + m][qn * 2 + n] = __builtin_amdgcn_mfma_f32_16x16x32_bf16(
                        af[m][ks], bfr[qn * 2 + n][ks], acc[qm * 4 + m][qn * 2 + n], 0, 0, 0);
        __builtin_amdgcn_s_setprio(0);
    };
    #define BAR() __builtin_amdgcn_s_barrier()

    // prologue: A(0),B(0) -> buf0; B(1) -> buf1 (A(1) staged at p0/p1 of iter 0)
    stageA(0, 0, 0); stageA(0, 1, 0);
    stageB(0, 0, 0); stageB(0, 1, 0);
    stageB(1, 0, 1); stageB(1, 1, 1);
    __builtin_amdgcn_s_waitcnt(0x0F74);   // vmcnt(4): A(0),B(0) landed
    BAR();

    for (int i = 0; i < NI; ++i) {
        const int t = 2 * i;
        const bool lastI = (i == NI - 1);
        // p0
        stageA(1, 0, t + 1);
        readAf(0, 0); readBf(0, 0);
        BAR(); mfmaQ(0, 0); BAR();
        // p1
        stageA(1, 1, t + 1);
        readBf(0, 1);
        BAR(); mfmaQ(0, 1); BAR();
        // p2
        if (!lastI) stageB(0, 0, t + 2);
        readAf(0, 1);
        BAR(); mfmaQ(1, 0); BAR();
        // p3
        if (!lastI) { stageB(0, 1, t + 2); __builtin_amdgcn_s_waitcnt(0x0F74); }
        else        { __builtin_amdgcn_s_waitcnt(0x0F70); }
        BAR(); mfmaQ(1, 1); BAR();
        // p4
        if (!lastI) stageA(0, 0, t + 2);
        readAf(1, 0); readBf(1, 0);
        BAR(); mfmaQ(0, 0); BAR();
        // p5
        if (!lastI) stageA(0, 1, t + 2);
        readBf(1, 1);
        BAR(); mfmaQ(0, 1); BAR();
        // p6
        if (!lastI) stageB(1, 0, t + 3);
        readAf(1, 1);
        BAR(); mfmaQ(1, 0); BAR();
        // p7
        if (!lastI) { stageB(1, 1, t + 3); __builtin_amdgcn_s_waitcnt(0x0F74); }
        BAR(); mfmaQ(1, 1); BAR();
    }
    #undef BAR

    // D layout: col = lane&15, row = (lane>>4)*4 + r (m89-verified)
    #pragma unroll
    for (int i = 0; i < 8; ++i) {
        #pragma unroll
        for (int j = 0; j < 4; ++j) {
            int gcol = n0 + wc * 64 + j * 16 + lm;
            if (EPI == 0 && gcol >= N) continue;
            #pragma unroll
            for (int r = 0; r < 4; ++r) {
                int grow = m0 + wr * 128 + i * 16 + kq * 4 + r;
                float v = acc[i][j][r];
                if (EPI == 2) atomicAdd(&Cf[(size_t)grow * ldc + gcol], v);
                else          Cb[(size_t)grow * ldc + gcol] = __float2bfloat16(v);
            }
        }
    }
}

// single 8-phase GEMM (2D grid + split-K over z)
template<int EPI, int KSPLIT, int SWZ>
__global__ __launch_bounds__(512, 2) void mfma8_gemm(
    const bf16* __restrict__ A, int lda,
    const bf16* __restrict__ Wt, int ldw,
    float* __restrict__ Cf, bf16* __restrict__ Cb, int ldc,
    int N, int K)
{
    __shared__ __align__(16) bf16 lds[4 * 16384];   // 128 KB
    int bx, by;
    if (SWZ >= 0) {
        int id = blockIdx.x + (int)(gridDim.x * blockIdx.y);
        remap<SWZ>(id, gridDim.x, bx, by);
    } else { bx = blockIdx.x; by = blockIdx.y; }
    const int Kc = K / KSPLIT;
    const int kbeg = (KSPLIT > 1) ? blockIdx.z * Kc : 0;
    gemm8_body<EPI>(lds, bx, by, A, lda, Wt, ldw, Cf, Cb, ldc, N, K, kbeg, Kc);
}

// dual 8-phase: Wf (64 blocks, long pole, dispatched first) + xz (128 blocks)
__global__ __launch_bounds__(512, 2) void mfma8_dual(
    const bf16* __restrict__ A0, int lda0, const bf16* __restrict__ Wt0, int ldw0,
    bf16* __restrict__ Cb0, int ldc0, int N0, int K0,
    const bf16* __restrict__ A1, int lda1, const bf16* __restrict__ Wt1, int ldw1,
    bf16* __restrict__ Cb1, int ldc1, int N1, int K1)
{
    __shared__ __align__(16) bf16 lds[4 * 16384];
    int id = blockIdx.x;
    const bf16 *A, *Wt; bf16* Cb; int lda, ldw, ldc, N, K, bx, by;
    if (id < 64) {        // Wf: 8x8 tiles, SWZ=0
        remap<0>(id, 8, bx, by);
        A = A0; lda = lda0; Wt = Wt0; ldw = ldw0; Cb = Cb0; ldc = ldc0; N = N0; K = K0;
    } else {              // xz: 16x8 tiles, SWZ=1
        remap<1>(id - 64, 16, bx, by);
        A = A1; lda = lda1; Wt = Wt1; ldw = ldw1; Cb = Cb1; ldc = ldc1; N = N1; K = K1;
    }
    gemm8_body<0>(lds, bx, by, A, lda, Wt, ldw, nullptr, Cb, ldc, N, K, 0, K);
}

// ---------------- old v6 GEMM (256 thr) — kept for the tiny BC sideband ----------
#define TM 128
#define TN 64
#define TK 64
// EPI==4: f32 atomicAdd into 32-col sideband (ld 32), cols >= 32 discarded
template<int EPI, int KSPLIT = 1, int SWZ = -1>
__global__ __launch_bounds__(256) void mfma_gemm(
    const bf16* __restrict__ A, int lda,
    const bf16* __restrict__ Wt, int ldw,
    float* __restrict__ Cf, bf16* __restrict__ Cb, int ldc,
    const float* __restrict__ bias,
    int N, int K)
{
    __shared__ __align__(16) bf16 As[2][TM * TK];
    __shared__ __align__(16) bf16 Bs[2][TN * TK];
    const int tid = threadIdx.x;
    const int wave = tid >> 6, lane = tid & 63;
    const int wm = (wave >> 1) * 64, wn = (wave & 1) * 32;
    int bx, by;
    if (SWZ >= 0) {
        int id = blockIdx.x + (int)(gridDim.x * blockIdx.y);
        remap<SWZ>(id, gridDim.x, bx, by);
    } else { bx = blockIdx.x; by = blockIdx.y; }
    const int m0 = by * TM, n0 = bx * TN;
    const int lm = lane & 15, kq = lane >> 4;
    const int srow = lane >> 3;
    const int schunk = (lane & 7) ^ srow;
    const bf16* gA = A + (size_t)(m0 + wave * 32 + srow) * lda + schunk * 8;
    const bf16* gB = Wt + (size_t)(n0 + wave * 16 + srow) * ldw + schunk * 8;
    const int Kc = K / KSPLIT;
    const int kbeg = (KSPLIT > 1) ? blockIdx.z * Kc : 0;
    const int NK = Kc / TK;
    f32x4 acc[4][2] = {};
    const int fsw = (lm & 7);

    auto stage = [&](int buf, int it) {
        const int k0 = kbeg + it * TK;
        bf16* lA = &As[buf][(wave * 32) * TK];
        bf16* lB = &Bs[buf][(wave * 16) * TK];
        #pragma unroll
        for (int g = 0; g < 4; ++g)
            load16_lds(gA + (size_t)(8 * g) * lda + k0, lA + (8 * g) * TK);
        #pragma unroll
        for (int g = 0; g < 2; ++g)
            load16_lds(gB + (size_t)(8 * g) * ldw + k0, lB + (8 * g) * TK);
    };
    auto compute = [&](int buf) {
        bf16x8 af[4][2], bfr[2][2];
        #pragma unroll
        for (int i = 0; i < 4; ++i)
            #pragma unroll
            for (int t = 0; t < 2; ++t)
                af[i][t] = *(const bf16x8*)(&As[buf][(wm + i * 16 + lm) * TK + ((t * 4 + kq) ^ fsw) * 8]);
        #pragma unroll
        for (int j = 0; j < 2; ++j)
            #pragma unroll
            for (int t = 0; t < 2; ++t)
                bfr[j][t] = *(const bf16x8*)(&Bs[buf][(wn + j * 16 + lm) * TK + ((t * 4 + kq) ^ fsw) * 8]);
        #pragma unroll
        for (int t = 0; t < 2; ++t)
            #pragma unroll
            for (int i = 0; i < 4; ++i)
                #pragma unroll
                for (int j = 0; j < 2; ++j)
                    acc[i][j] = __builtin_amdgcn_mfma_f32_16x16x32_bf16(af[i][t], bfr[j][t], acc[i][j], 0, 0, 0);
    };

    stage(0, 0);
    for (int it = 0; it < NK; it += 2) {
        stage(1, it + 1);
        __builtin_amdgcn_s_waitcnt(0x0F76);
        __builtin_amdgcn_s_barrier();
        compute(0);
        __builtin_amdgcn_s_barrier();
        if (it + 2 < NK) {
            stage(0, it + 2);
            __builtin_amdgcn_s_waitcnt(0x0F76);
        } else {
            __builtin_amdgcn_s_waitcnt(0x0F70);
        }
        __builtin_amdgcn_s_barrier();
        compute(1);
        __builtin_amdgcn_s_barrier();
    }

    #pragma unroll
    for (int i = 0; i < 4; ++i) {
        #pragma unroll
        for (int j = 0; j < 2; ++j) {
            int gcol = n0 + wn + j * 16 + lm;
            if ((EPI == 0 || EPI == 4) && gcol >= N) continue;
            #pragma unroll
            for (int r = 0; r < 4; ++r) {
                int grow = m0 + wm + i * 16 + kq * 4 + r;
                float v = acc[i][j][r];
                if (EPI == 4)      atomicAdd(&Cf[(size_t)grow * 32 + gcol], v);
                else if (EPI == 2) atomicAdd(&Cf[(size_t)grow * ldc + gcol], v);
                else               Cb[(size_t)grow * ldc + gcol] = __float2bfloat16(v);
            }
        }
    }
}

// ---------------- depthwise causal conv (k=4) + bias + SiLU (bf16 io, 8 ch/thread) ----
__global__ void conv_silu_kernel(const bf16* __restrict__ xz,
                                 const float* __restrict__ conv_w,
                                 const float* __restrict__ conv_b,
                                 bf16* __restrict__ u)
{
    int idx = blockIdx.x * blockDim.x + threadIdx.x;   // over BB*LL*DINNER/8
    int d8 = idx & (DINNER / 8 - 1);
    int l  = (idx >> 8) & (LL - 1);
    int b  = idx >> 18;
    int d0 = d8 * 8;

    float acc[8];
    {
        float4 b0 = *(const float4*)(conv_b + d0);
        float4 b1 = *(const float4*)(conv_b + d0 + 4);
        acc[0] = b0.x; acc[1] = b0.y; acc[2] = b0.z; acc[3] = b0.w;
        acc[4] = b1.x; acc[5] = b1.y; acc[6] = b1.z; acc[7] = b1.w;
    }
    #pragma unroll
    for (int j = 0; j < DCONV; ++j) {
        int ll = l - (DCONV - 1) + j;
        if (ll >= 0) {
            bf16x8 v = *(const bf16x8*)(xz + ((size_t)(b * LL + ll)) * N_XZ + d0);
            #pragma unroll
            for (int r = 0; r < 8; ++r) {
                float xv = __uint_as_float(((unsigned)(unsigned short)v[r]) << 16);
                acc[r] = fmaf(conv_w[(d0 + r) * DCONV + j], xv, acc[r]);
            }
        }
    }
    bf16x8 out;
    #pragma unroll
    for (int r = 0; r < 8; ++r) {
        float y = acc[r] / (1.f + __expf(-acc[r]));
        bf16 h = __float2bfloat16(y);
        out[r] = *reinterpret_cast<short*>(&h);
    }
    *(bf16x8*)(u + ((size_t)(b * LL + l)) * DINNER + d0) = out;
}

// ---------------- scan phase A: lane per (b,d,chunk), h[16] in regs -----------------
// dt input is now RAW (pre-softplus, atomic-accumulated f32); softplus+bias here.
__global__ __launch_bounds__(256) void scan_phase_a(
    const float* __restrict__ dt, const bf16* __restrict__ u,
    const float* __restrict__ BC, const float* __restrict__ A_log,
    const float* __restrict__ dtb,
    float* __restrict__ chunkP, float* __restrict__ chunkH)
{
    const int d = blockIdx.x * 256 + threadIdx.x;
    const int c = blockIdx.y, b = blockIdx.z;
    const int l0 = c * LCH;

    float A[DSTATE];
    {
        const f32x4* ap = (const f32x4*)(A_log + d * DSTATE);
        #pragma unroll
        for (int q = 0; q < 4; ++q) {
            f32x4 v = ap[q];
            #pragma unroll
            for (int r = 0; r < 4; ++r) A[q * 4 + r] = -__expf(v[r]);
        }
    }
    const float bd = dtb[d];
    float h[DSTATE];
    #pragma unroll
    for (int n = 0; n < DSTATE; ++n) h[n] = 0.f;
    float sdt = 0.f;

    const float* dtp = dt + ((size_t)b * LL + l0) * DINNER + d;
    const bf16* up = u + ((size_t)b * LL + l0) * DINNER + d;
    const float* bcp = BC + ((size_t)b * LL + l0) * 32;

    #pragma unroll 2
    for (int i = 0; i < LCH; ++i) {
        float dtv = *dtp + bd;
        dtv = (dtv > 20.f) ? dtv : log1pf(__expf(dtv));
        float uv  = (float)*up;
        float du  = dtv * uv;
        f32x4 Bv[4];
        #pragma unroll
        for (int q = 0; q < 4; ++q) Bv[q] = *(const f32x4*)(bcp + q * 4);
        #pragma unroll
        for (int n = 0; n < DSTATE; ++n) {
            float a = __expf(dtv * A[n]);
            h[n] = fmaf(a, h[n], du * Bv[n >> 2][n & 3]);
        }
        sdt += dtv;
        dtp += DINNER; up += DINNER; bcp += 32;
    }

    size_t idx = (((size_t)b * CCH + c) * DINNER + d) * DSTATE;
    #pragma unroll
    for (int q = 0; q < 4; ++q) {
        f32x4 pv, hv;
        #pragma unroll
        for (int r = 0; r < 4; ++r) { pv[r] = __expf(A[q * 4 + r] * sdt); hv[r] = h[q * 4 + r]; }
        *(f32x4*)(chunkP + idx + q * 4) = pv;
        *(f32x4*)(chunkH + idx + q * 4) = hv;
    }
}

// ---------------- scan phase P: exclusive prefix over chunks, in place on chunkH ----
__global__ __launch_bounds__(256) void scan_phase_p(
    const float* __restrict__ chunkP, float* __restrict__ chunkH)
{
    int gid = blockIdx.x * 256 + threadIdx.x;   // over B*DINNER*DSTATE = 65536
    int n = gid & 15;
    int d = (gid >> 4) & (DINNER - 1);
    int b = gid >> 15;
    const size_t stride = (size_t)DINNER * DSTATE;
    size_t idx = ((size_t)b * CCH * DINNER + d) * DSTATE + n;
    float H = 0.f;
    for (int c = 0; c < CCH; ++c) {
        float P  = chunkP[idx];
        float hl = chunkH[idx];
        chunkH[idx] = H;           // exclusive prefix
        H = fmaf(P, H, hl);
        idx += stride;
    }
}

// ---------------- scan phase B: lane per (b,d,chunk); gated y over u --------
__global__ __launch_bounds__(256) void scan_phase_b(
    const float* __restrict__ dt, bf16* __restrict__ u,
    const float* __restrict__ BC, const bf16* __restrict__ xz,
    const float* __restrict__ A_log, const float* __restrict__ Dp,
    const float* __restrict__ dtb,
    const float* __restrict__ chunkH)
{
    const int d = blockIdx.x * 256 + threadIdx.x;
    const int c = blockIdx.y, b = blockIdx.z;
    const int l0 = c * LCH;

    float A[DSTATE];
    {
        const f32x4* ap = (const f32x4*)(A_log + d * DSTATE);
        #pragma unroll
        for (int q = 0; q < 4; ++q) {
            f32x4 v = ap[q];
            #pragma unroll
            for (int r = 0; r < 4; ++r) A[q * 4 + r] = -__expf(v[r]);
        }
    }
    const float Dd = Dp[d];
    const float bd = dtb[d];
    float h[DSTATE];
    {
        size_t idx = (((size_t)b * CCH + c) * DINNER + d) * DSTATE;
        #pragma unroll
        for (int q = 0; q < 4; ++q) {
            f32x4 v = *(const f32x4*)(chunkH + idx + q * 4);
            #pragma unroll
            for (int r = 0; r < 4; ++r) h[q * 4 + r] = v[r];
        }
    }

    const float* dtp = dt + ((size_t)b * LL + l0) * DINNER + d;
    bf16* up = u + ((size_t)b * LL + l0) * DINNER + d;
    const float* bcp = BC + ((size_t)b * LL + l0) * 32;
    const bf16* zp = xz + ((size_t)b * LL + l0) * N_XZ + DINNER + d;

    #pragma unroll 2
    for (int i = 0; i < LCH; ++i) {
        float dtv = *dtp + bd;
        dtv = (dtv > 20.f) ? dtv : log1pf(__expf(dtv));
        float uv  = (float)*up;
        float du  = dtv * uv;
        f32x4 Bv[4], Cv[4];
        #pragma unroll
        for (int q = 0; q < 4; ++q) {
            Bv[q] = *(const f32x4*)(bcp + q * 4);
            Cv[q] = *(const f32x4*)(bcp + 16 + q * 4);
        }
        float acc = 0.f;
        #pragma unroll
        for (int n = 0; n < DSTATE; ++n) {
            float a = __expf(dtv * A[n]);
            h[n] = fmaf(a, h[n], du * Bv[n >> 2][n & 3]);
            acc = fmaf(h[n], Cv[n >> 2][n & 3], acc);
        }
        float zv = (float)*zp;
        acc = fmaf(Dd, uv, acc);
        acc *= zv / (1.f + __expf(-zv));
        *up = __float2bfloat16(acc);
        dtp += DINNER; up += DINNER; bcp += 32; zp += N_XZ;
    }
}

extern "C" void kernel_launch(void* const* d_in, const int* in_sizes, int n_in,
                              void* d_out, int out_size, void* d_ws, size_t ws_size,
                              hipStream_t stream) {
    const float* x         = (const float*)d_in[0];
    const float* in_proj_w = (const float*)d_in[1];
    const float* conv_w    = (const float*)d_in[2];
    const float* conv_b    = (const float*)d_in[3];
    const float* x_proj_w  = (const float*)d_in[4];
    const float* dt_proj_w = (const float*)d_in[5];
    const float* dt_proj_b = (const float*)d_in[6];
    const float* A_log     = (const float*)d_in[7];
    const float* Dp        = (const float*)d_in[8];
    const float* out_proj_w= (const float*)d_in[9];
    float* out = (float*)d_out;

    // workspace layout (~80.7 MB, unchanged from r3); xbf aliases dt (xbf dead
    // after megaA; dt zeroed after megaA, then atomic-accumulated in megaB).
    char* p = (char*)d_ws;
    float* dt   = (float*)p;                          p += (size_t)MM * DINNER * 4;       // 16.8 MB
    bf16*  xbf  = (bf16*)dt;
    bf16*  xz   = (bf16*)p;                           p += (size_t)MM * N_XZ * 2;         // 16.8 MB
    bf16*  u    = (bf16*)p;                           p += (size_t)MM * DINNER * 2;       // 8.4 MB
    bf16*  wft  = (bf16*)p;                           p += (size_t)MM * N_SSM * 2;        // slot 8.5 MB
    bf16*  Wt1  = (bf16*)p;                           p += (size_t)N_XZ * DMODEL * 2;     // 8.4 MB
    bf16*  w2slot = (bf16*)p;                         p += (size_t)N_SSM_PAD * DINNER * 2;// 8.9 MB
    bf16*  W2bf = w2slot;
    bf16*  w2bc = w2slot + (size_t)DINNER * N_SSM;    // 32x2048 slot tail
    bf16*  Wt3  = (bf16*)p;                           p += (size_t)DINNER * DINNER * 2;   // 8.4 MB
    bf16*  Wt4  = (bf16*)p;                           p += (size_t)DMODEL * DINNER * 2;   // 4.2 MB
    float* BC   = (float*)p;                          p += (size_t)MM * 32 * 4;           // 256 KB
    float* chunkP = (float*)Wt1;     // Wt1 dead after megaA
    float* chunkH = (float*)w2slot;  // W2bf dead after megaB

    // 0) prep: W1/W3/W4 transposes + W2 cvt + W2[:, :32] transpose + x cvt
    prep_kernel<<<16512, 256, 0, stream>>>(x, xbf, in_proj_w, Wt1, dt_proj_w, Wt3,
                                           out_proj_w, Wt4, x_proj_w, W2bf, w2bc);
    // 1) megaA (192 blocks, 8-phase): Wf^T = W3t @ W2dt (64 blocks, long pole first)
    //    + xz = xbf @ W1t (128 blocks)
    mfma8_dual<<<192, 512, 0, stream>>>(
        Wt3, DINNER, W2bf + 32, N_SSM, wft, DINNER, DINNER, DINNER,
        xbf, DMODEL, Wt1, DMODEL, xz, N_XZ, N_XZ, DMODEL);
    // zero atomic accumulators (xbf/dt alias free only after megaA)
    hipMemsetAsync(dt, 0, (size_t)MM * DINNER * 4, stream);
    hipMemsetAsync(BC, 0, (size_t)MM * 32 * 4, stream);
    hipMemsetAsync(out, 0, (size_t)out_size * sizeof(float), stream);
    // 2) u = silu(conv(x_inner)+b)
    {
        int n = BB * LL * DINNER / 8;
        conv_silu_kernel<<<(n + 255) / 256, 256, 0, stream>>>(xz, conv_w, conv_b, u);
    }
    // 3) dt_raw = u @ Wf (2048x2048, K=2048), 8-phase split-K=2 atomic (128 blocks)
    mfma8_gemm<2, 2, 0><<<dim3(8, 8, 2), 512, 0, stream>>>(
        u, DINNER, wft, DINNER, dt, nullptr, DINNER, DINNER, DINNER);
    // 4) BC = u @ W2[:, :32] (2048x32, K=2048), old kernel split-K=8 atomic (128 blocks)
    mfma_gemm<4, 8, -1><<<dim3(1, 16, 8), 256, 0, stream>>>(
        u, DINNER, w2bc, DINNER, BC, nullptr, 32, nullptr, 32, DINNER);
    // 5) chunked selective scan (softplus(dt_raw + bias) applied on read)
    scan_phase_a<<<dim3(DINNER / 256, CCH, BB), 256, 0, stream>>>(dt, u, BC, A_log, dt_proj_b, chunkP, chunkH);
    scan_phase_p<<<dim3(BB * DINNER * DSTATE / 256), 256, 0, stream>>>(chunkP, chunkH);
    scan_phase_b<<<dim3(DINNER / 256, CCH, BB), 256, 0, stream>>>(dt, u, BC, xz, A_log, Dp, dt_proj_b, chunkH);
    // 6) out = y @ W4 (2048x1024, K=2048), 8-phase split-K=4 atomic (128 blocks)
    mfma8_gemm<2, 4, -1><<<dim3(4, 8, 4), 512, 0, stream>>>(
        u, DINNER, Wt4, DINNER, out, nullptr, DMODEL, DMODEL, DINNER);
}

// Round 6
// 383.007 us; speedup vs baseline: 1.0580x; 1.0580x over previous
//
#include <hip/hip_runtime.h>
#include <hip/hip_bf16.h>

// Dims (fixed for this problem)
#define BB 2
#define LL 1024
#define DMODEL 1024
#define DINNER 2048
#define DSTATE 16
#define DCONV 4
#define MM (BB * LL)          // 2048
#define N_XZ 4096
#define N_SSM 2080
#define N_SSM_PAD 2176        // 34 * 64
#define CCH 32                // chunks over L
#define LCH 32                // chunk length (CCH*LCH == LL)

typedef __hip_bfloat16 bf16;
typedef short bf16x8 __attribute__((ext_vector_type(8)));
typedef float f32x4 __attribute__((ext_vector_type(4)));

// ---------------- async global -> LDS, 16B per lane ----------------
__device__ __forceinline__ void load16_lds(const bf16* g, bf16* l) {
    __builtin_amdgcn_global_load_lds(
        (const __attribute__((address_space(1))) void*)g,
        (__attribute__((address_space(3))) void*)l,
        16, 0, 0);
}

template<int SWZ>
__device__ __forceinline__ void remap(int id, int NX, int& bx, int& by) {
    if (SWZ >= 0) {   // bind XCD (id&7) to a contiguous 2^SWZ range of n-tiles
        int xcd = id & 7, slot = id >> 3;
        bx = (xcd << SWZ) + (slot & ((1 << SWZ) - 1));
        by = slot >> SWZ;
    } else { bx = id % NX; by = id / NX; }
}

// ---------------- fused prep: 3 weight transposes + W2 cvt + BC-slice transpose + x cvt
__global__ __launch_bounds__(256) void prep_kernel(
    const float* __restrict__ x, bf16* __restrict__ xbf,
    const float* __restrict__ w1, bf16* __restrict__ o1,
    const float* __restrict__ w3, bf16* __restrict__ o3,
    const float* __restrict__ w4, bf16* __restrict__ o4,
    const float* __restrict__ w2, bf16* __restrict__ w2bf,
    bf16* __restrict__ w2bc)
{
    int bid = blockIdx.x;
    if (bid >= 14464) {                 // x cvt: 2048 blocks x 1024 elems
        bid -= 14464;
        int i = (bid * 256 + threadIdx.x) * 4;
        float4 v = *(const float4*)(x + i);
        xbf[i + 0] = __float2bfloat16(v.x);
        xbf[i + 1] = __float2bfloat16(v.y);
        xbf[i + 2] = __float2bfloat16(v.z);
        xbf[i + 3] = __float2bfloat16(v.w);
        return;
    }
    if (bid >= 10240 && bid < 14400) {  // w2 cvt: 2048*2080 f32 -> bf16, 4160 blocks
        bid -= 10240;
        int i = (bid * 256 + threadIdx.x) * 4;
        float4 v = *(const float4*)(w2 + i);
        w2bf[i + 0] = __float2bfloat16(v.x);
        w2bf[i + 1] = __float2bfloat16(v.y);
        w2bf[i + 2] = __float2bfloat16(v.z);
        w2bf[i + 3] = __float2bfloat16(v.w);
        return;
    }
    const float* src; bf16* dst; int K, N, tn, tk, srcld;
    if (bid < 4096)        { src = w1; dst = o1; K = 1024; N = 4096; tn = bid & 127; tk = bid >> 7; srcld = N; }
    else if (bid < 8192)   { bid -= 4096; src = w3; dst = o3; K = 2048; N = 2048; tn = bid & 63; tk = bid >> 6; srcld = N; }
    else if (bid < 10240)  { bid -= 8192; src = w4; dst = o4; K = 2048; N = 1024; tn = bid & 31; tk = bid >> 5; srcld = N; }
    else                   { bid -= 14400; src = w2; dst = w2bc; K = 2048; N = 32; tn = 0; tk = bid; srcld = N_SSM; }
    __shared__ float tile[32][33];
    const int nb = tn * 32, kb = tk * 32;
    const int tx = threadIdx.x & 31, ty = threadIdx.x >> 5;
    #pragma unroll
    for (int i = 0; i < 32; i += 8) {
        int k = kb + ty + i, n = nb + tx;
        tile[ty + i][tx] = (k < K && n < N) ? src[(size_t)k * srcld + n] : 0.f;
    }
    __syncthreads();
    #pragma unroll
    for (int i = 0; i < 32; i += 8) {
        int n = nb + ty + i, k = kb + tx;
        if (n < N && k < K) dst[(size_t)n * K + k] = __float2bfloat16(tile[tx][ty + i]);
    }
}

// ========== MFMA GEMM v12: 128x128 tile, 4 waves x (64x64) — m103 geometry ==========
// v6-verified 2-buf schedule (counted vmcnt, never drain mid-loop) + session-verified
// XOR chunk swizzle (SQ_LDS_BANK_CONFLICT==0). 8 loads/wave/stage -> vmcnt(8).
// 64 KB LDS -> 2 blocks/CU (8 waves/CU). Wave tile 64x64 doubles FLOP/LDS-byte vs v6.
// C[M,N] = A[M,K](bf16) @ Wt[N,K](bf16)^T
// EPI: 0 = bf16 store (col<N guard), 1 = +bias softplus f32, 2 = f32 (atomic if at),
//      3 = cols<32 -> f32 sideband (ld 32), cols >= 32 discarded
#define TM 128
#define TN 128
#define TK 64

template<int EPI>
__device__ __forceinline__ void gemm_body(
    bf16* AsB, bf16* BsB, int bx, int by,
    const bf16* __restrict__ A, int lda,
    const bf16* __restrict__ Wt, int ldw,
    float* __restrict__ Cf, bf16* __restrict__ Cb, int ldc,
    const float* __restrict__ bias,
    int N, int K, int kbeg, int Kc, bool at)
{
    const int tid = threadIdx.x;
    const int wave = tid >> 6, lane = tid & 63;
    const int wm = (wave >> 1) * 64, wn = (wave & 1) * 64;
    const int m0 = by * TM, n0 = bx * TN;
    const int lm = lane & 15, kq = lane >> 4;

    // staging: lane covers row (lane>>3), swizzled chunk (lane&7)^row
    const int srow = lane >> 3;
    const int schunk = (lane & 7) ^ srow;
    const bf16* gA = A  + (size_t)(m0 + wave * 32 + srow) * lda + schunk * 8;
    const bf16* gB = Wt + (size_t)(n0 + wave * 32 + srow) * ldw + schunk * 8;

    const int NK = Kc / TK;   // even for all call sites
    f32x4 acc[4][4] = {};
    const int fsw = lm & 7;   // frag-read XOR key

    auto stage = [&](int buf, int it) {
        const int k0 = kbeg + it * TK;
        bf16* lA = AsB + buf * (TM * TK) + (wave * 32) * TK;
        bf16* lB = BsB + buf * (TN * TK) + (wave * 32) * TK;
        #pragma unroll
        for (int g = 0; g < 4; ++g) {
            load16_lds(gA + (size_t)(8 * g) * lda + k0, lA + (8 * g) * TK);
            load16_lds(gB + (size_t)(8 * g) * ldw + k0, lB + (8 * g) * TK);
        }
    };  // 8 loads per wave per stage
    auto compute = [&](int buf) {
        const bf16* Asb = AsB + buf * (TM * TK);
        const bf16* Bsb = BsB + buf * (TN * TK);
        bf16x8 af[4][2], bfr[4][2];
        #pragma unroll
        for (int i = 0; i < 4; ++i)
            #pragma unroll
            for (int t = 0; t < 2; ++t)
                af[i][t] = *(const bf16x8*)(&Asb[(wm + i * 16 + lm) * TK + ((t * 4 + kq) ^ fsw) * 8]);
        #pragma unroll
        for (int j = 0; j < 4; ++j)
            #pragma unroll
            for (int t = 0; t < 2; ++t)
                bfr[j][t] = *(const bf16x8*)(&Bsb[(wn + j * 16 + lm) * TK + ((t * 4 + kq) ^ fsw) * 8]);
        #pragma unroll
        for (int t = 0; t < 2; ++t)
            #pragma unroll
            for (int i = 0; i < 4; ++i)
                #pragma unroll
                for (int j = 0; j < 4; ++j)
                    acc[i][j] = __builtin_amdgcn_mfma_f32_16x16x32_bf16(af[i][t], bfr[j][t], acc[i][j], 0, 0, 0);
    };

    stage(0, 0);                                  // 8 in flight
    for (int it = 0; it < NK; it += 2) {
        stage(1, it + 1);                         // 16 in flight
        __builtin_amdgcn_s_waitcnt(0x0F78);       // vmcnt(8): buf0 done, buf1 flying
        __builtin_amdgcn_s_barrier();
        compute(0);
        __builtin_amdgcn_s_barrier();
        if (it + 2 < NK) {
            stage(0, it + 2);
            __builtin_amdgcn_s_waitcnt(0x0F78);   // buf1 done, buf0 flying
        } else {
            __builtin_amdgcn_s_waitcnt(0x0F70);   // vmcnt(0)
        }
        __builtin_amdgcn_s_barrier();
        compute(1);
        __builtin_amdgcn_s_barrier();
    }

    // D layout: col = lane&15, row = (lane>>4)*4 + r (m89-verified)
    #pragma unroll
    for (int i = 0; i < 4; ++i) {
        #pragma unroll
        for (int j = 0; j < 4; ++j) {
            int gcol = n0 + wn + j * 16 + lm;
            if ((EPI == 0 || EPI == 3) && gcol >= N) continue;
            #pragma unroll
            for (int r = 0; r < 4; ++r) {
                int grow = m0 + wm + i * 16 + kq * 4 + r;
                float v = acc[i][j][r];
                if (EPI == 1) {
                    v += bias[gcol];
                    v = (v > 20.f) ? v : log1pf(__expf(v));
                    Cf[(size_t)grow * ldc + gcol] = v;
                } else if (EPI == 2) {
                    if (at) atomicAdd(&Cf[(size_t)grow * ldc + gcol], v);
                    else    Cf[(size_t)grow * ldc + gcol] = v;
                } else if (EPI == 3) {
                    Cf[(size_t)grow * 32 + gcol] = v;      // f32 sideband (N<=32)
                } else {
                    Cb[(size_t)grow * ldc + gcol] = __float2bfloat16(v);
                }
            }
        }
    }
}

// single-GEMM wrapper (2D grid + optional split-K over z)
template<int EPI, int KSPLIT = 1, int SWZ = -1>
__global__ __launch_bounds__(256, 2) void mfma_gemm(
    const bf16* __restrict__ A, int lda,
    const bf16* __restrict__ Wt, int ldw,
    float* __restrict__ Cf, bf16* __restrict__ Cb, int ldc,
    const float* __restrict__ bias,
    int N, int K)
{
    __shared__ __align__(16) bf16 As[2 * TM * TK];   // 32 KB
    __shared__ __align__(16) bf16 Bs[2 * TN * TK];   // 32 KB
    int bx, by;
    if (SWZ >= 0) {
        int id = blockIdx.x + (int)(gridDim.x * blockIdx.y);
        remap<SWZ>(id, gridDim.x, bx, by);
    } else { bx = blockIdx.x; by = blockIdx.y; }
    const int Kc = K / KSPLIT;
    const int kbeg = (KSPLIT > 1) ? blockIdx.z * Kc : 0;
    gemm_body<EPI>(As, Bs, bx, by, A, lda, Wt, ldw, Cf, Cb, ldc,
                   bias, N, K, kbeg, Kc, KSPLIT > 1);
}

// dual-GEMM: two independent GEMMs in ONE launch; split-K per sub via KS templates.
// sub0 occupies ids [0, nblk0) with nblk0 = tiles0 * KS0 (long-pole sub goes first).
template<int EPI0, int KS0, int SWZ0, int EPI1, int KS1, int SWZ1>
__global__ __launch_bounds__(256, 2) void mfma_gemm_dual(
    int nblk0, int NX0,
    const bf16* __restrict__ A0, int lda0, const bf16* __restrict__ Wt0, int ldw0,
    float* __restrict__ Cf0, bf16* __restrict__ Cb0, int ldc0,
    const float* __restrict__ bias0, int N0, int K0,
    int NX1,
    const bf16* __restrict__ A1, int lda1, const bf16* __restrict__ Wt1, int ldw1,
    float* __restrict__ Cf1, bf16* __restrict__ Cb1, int ldc1,
    const float* __restrict__ bias1, int N1, int K1)
{
    __shared__ __align__(16) bf16 As[2 * TM * TK];
    __shared__ __align__(16) bf16 Bs[2 * TN * TK];
    int id = blockIdx.x;
    if (id < nblk0) {
        int kz = (KS0 > 1) ? id % KS0 : 0;
        int tl = (KS0 > 1) ? id / KS0 : id;
        int bx, by; remap<SWZ0>(tl, NX0, bx, by);
        const int Kc = K0 / KS0;
        gemm_body<EPI0>(As, Bs, bx, by, A0, lda0, Wt0, ldw0,
                        Cf0, Cb0, ldc0, bias0, N0, K0, kz * Kc, Kc, KS0 > 1);
    } else {
        id -= nblk0;
        int kz = (KS1 > 1) ? id % KS1 : 0;
        int tl = (KS1 > 1) ? id / KS1 : id;
        int bx, by; remap<SWZ1>(tl, NX1, bx, by);
        const int Kc = K1 / KS1;
        gemm_body<EPI1>(As, Bs, bx, by, A1, lda1, Wt1, ldw1,
                        Cf1, Cb1, ldc1, bias1, N1, K1, kz * Kc, Kc, KS1 > 1);
    }
}

// ---------------- depthwise causal conv (k=4) + bias + SiLU (bf16 io, 8 ch/thread) ----
__global__ void conv_silu_kernel(const bf16* __restrict__ xz,
                                 const float* __restrict__ conv_w,
                                 const float* __restrict__ conv_b,
                                 bf16* __restrict__ u)
{
    int idx = blockIdx.x * blockDim.x + threadIdx.x;   // over BB*LL*DINNER/8
    int d8 = idx & (DINNER / 8 - 1);
    int l  = (idx >> 8) & (LL - 1);
    int b  = idx >> 18;
    int d0 = d8 * 8;

    float acc[8];
    {
        float4 b0 = *(const float4*)(conv_b + d0);
        float4 b1 = *(const float4*)(conv_b + d0 + 4);
        acc[0] = b0.x; acc[1] = b0.y; acc[2] = b0.z; acc[3] = b0.w;
        acc[4] = b1.x; acc[5] = b1.y; acc[6] = b1.z; acc[7] = b1.w;
    }
    #pragma unroll
    for (int j = 0; j < DCONV; ++j) {
        int ll = l - (DCONV - 1) + j;
        if (ll >= 0) {
            bf16x8 v = *(const bf16x8*)(xz + ((size_t)(b * LL + ll)) * N_XZ + d0);
            #pragma unroll
            for (int r = 0; r < 8; ++r) {
                float xv = __uint_as_float(((unsigned)(unsigned short)v[r]) << 16);
                acc[r] = fmaf(conv_w[(d0 + r) * DCONV + j], xv, acc[r]);
            }
        }
    }
    bf16x8 out;
    #pragma unroll
    for (int r = 0; r < 8; ++r) {
        float y = acc[r] / (1.f + __expf(-acc[r]));
        bf16 h = __float2bfloat16(y);
        out[r] = *reinterpret_cast<short*>(&h);
    }
    *(bf16x8*)(u + ((size_t)(b * LL + l)) * DINNER + d0) = out;
}

// ---------------- scan phase A: lane per (b,d,chunk), h[16] in regs -----------------
// dt input is RAW (pre-softplus, atomic-accumulated f32); softplus+bias on read.
__global__ __launch_bounds__(256) void scan_phase_a(
    const float* __restrict__ dt, const bf16* __restrict__ u,
    const float* __restrict__ BC, const float* __restrict__ A_log,
    const float* __restrict__ dtb,
    float* __restrict__ chunkP, float* __restrict__ chunkH)
{
    const int d = blockIdx.x * 256 + threadIdx.x;
    const int c = blockIdx.y, b = blockIdx.z;
    const int l0 = c * LCH;

    float A[DSTATE];
    {
        const f32x4* ap = (const f32x4*)(A_log + d * DSTATE);
        #pragma unroll
        for (int q = 0; q < 4; ++q) {
            f32x4 v = ap[q];
            #pragma unroll
            for (int r = 0; r < 4; ++r) A[q * 4 + r] = -__expf(v[r]);
        }
    }
    const float bd = dtb[d];
    float h[DSTATE];
    #pragma unroll
    for (int n = 0; n < DSTATE; ++n) h[n] = 0.f;
    float sdt = 0.f;

    const float* dtp = dt + ((size_t)b * LL + l0) * DINNER + d;
    const bf16* up = u + ((size_t)b * LL + l0) * DINNER + d;
    const float* bcp = BC + ((size_t)b * LL + l0) * 32;

    #pragma unroll 2
    for (int i = 0; i < LCH; ++i) {
        float dtv = *dtp + bd;
        dtv = (dtv > 20.f) ? dtv : log1pf(__expf(dtv));
        float uv  = (float)*up;
        float du  = dtv * uv;
        f32x4 Bv[4];
        #pragma unroll
        for (int q = 0; q < 4; ++q) Bv[q] = *(const f32x4*)(bcp + q * 4);
        #pragma unroll
        for (int n = 0; n < DSTATE; ++n) {
            float a = __expf(dtv * A[n]);
            h[n] = fmaf(a, h[n], du * Bv[n >> 2][n & 3]);
        }
        sdt += dtv;
        dtp += DINNER; up += DINNER; bcp += 32;
    }

    size_t idx = (((size_t)b * CCH + c) * DINNER + d) * DSTATE;
    #pragma unroll
    for (int q = 0; q < 4; ++q) {
        f32x4 pv, hv;
        #pragma unroll
        for (int r = 0; r < 4; ++r) { pv[r] = __expf(A[q * 4 + r] * sdt); hv[r] = h[q * 4 + r]; }
        *(f32x4*)(chunkP + idx + q * 4) = pv;
        *(f32x4*)(chunkH + idx + q * 4) = hv;
    }
}

// ---------------- scan phase P: exclusive prefix over chunks, in place on chunkH ----
__global__ __launch_bounds__(256) void scan_phase_p(
    const float* __restrict__ chunkP, float* __restrict__ chunkH)
{
    int gid = blockIdx.x * 256 + threadIdx.x;   // over B*DINNER*DSTATE = 65536
    int n = gid & 15;
    int d = (gid >> 4) & (DINNER - 1);
    int b = gid >> 15;
    const size_t stride = (size_t)DINNER * DSTATE;
    size_t idx = ((size_t)b * CCH * DINNER + d) * DSTATE + n;
    float H = 0.f;
    for (int c = 0; c < CCH; ++c) {
        float P  = chunkP[idx];
        float hl = chunkH[idx];
        chunkH[idx] = H;           // exclusive prefix
        H = fmaf(P, H, hl);
        idx += stride;
    }
}

// ---------------- scan phase B: lane per (b,d,chunk); gated y over u --------
__global__ __launch_bounds__(256) void scan_phase_b(
    const float* __restrict__ dt, bf16* __restrict__ u,
    const float* __restrict__ BC, const bf16* __restrict__ xz,
    const float* __restrict__ A_log, const float* __restrict__ Dp,
    const float* __restrict__ dtb,
    const float* __restrict__ chunkH)
{
    const int d = blockIdx.x * 256 + threadIdx.x;
    const int c = blockIdx.y, b = blockIdx.z;
    const int l0 = c * LCH;

    float A[DSTATE];
    {
        const f32x4* ap = (const f32x4*)(A_log + d * DSTATE);
        #pragma unroll
        for (int q = 0; q < 4; ++q) {
            f32x4 v = ap[q];
            #pragma unroll
            for (int r = 0; r < 4; ++r) A[q * 4 + r] = -__expf(v[r]);
        }
    }
    const float Dd = Dp[d];
    const float bd = dtb[d];
    float h[DSTATE];
    {
        size_t idx = (((size_t)b * CCH + c) * DINNER + d) * DSTATE;
        #pragma unroll
        for (int q = 0; q < 4; ++q) {
            f32x4 v = *(const f32x4*)(chunkH + idx + q * 4);
            #pragma unroll
            for (int r = 0; r < 4; ++r) h[q * 4 + r] = v[r];
        }
    }

    const float* dtp = dt + ((size_t)b * LL + l0) * DINNER + d;
    bf16* up = u + ((size_t)b * LL + l0) * DINNER + d;
    const float* bcp = BC + ((size_t)b * LL + l0) * 32;
    const bf16* zp = xz + ((size_t)b * LL + l0) * N_XZ + DINNER + d;

    #pragma unroll 2
    for (int i = 0; i < LCH; ++i) {
        float dtv = *dtp + bd;
        dtv = (dtv > 20.f) ? dtv : log1pf(__expf(dtv));
        float uv  = (float)*up;
        float du  = dtv * uv;
        f32x4 Bv[4], Cv[4];
        #pragma unroll
        for (int q = 0; q < 4; ++q) {
            Bv[q] = *(const f32x4*)(bcp + q * 4);
            Cv[q] = *(const f32x4*)(bcp + 16 + q * 4);
        }
        float acc = 0.f;
        #pragma unroll
        for (int n = 0; n < DSTATE; ++n) {
            float a = __expf(dtv * A[n]);
            h[n] = fmaf(a, h[n], du * Bv[n >> 2][n & 3]);
            acc = fmaf(h[n], Cv[n >> 2][n & 3], acc);
        }
        float zv = (float)*zp;
        acc = fmaf(Dd, uv, acc);
        acc *= zv / (1.f + __expf(-zv));
        *up = __float2bfloat16(acc);
        dtp += DINNER; up += DINNER; bcp += 32; zp += N_XZ;
    }
}

extern "C" void kernel_launch(void* const* d_in, const int* in_sizes, int n_in,
                              void* d_out, int out_size, void* d_ws, size_t ws_size,
                              hipStream_t stream) {
    const float* x         = (const float*)d_in[0];
    const float* in_proj_w = (const float*)d_in[1];
    const float* conv_w    = (const float*)d_in[2];
    const float* conv_b    = (const float*)d_in[3];
    const float* x_proj_w  = (const float*)d_in[4];
    const float* dt_proj_w = (const float*)d_in[5];
    const float* dt_proj_b = (const float*)d_in[6];
    const float* A_log     = (const float*)d_in[7];
    const float* Dp        = (const float*)d_in[8];
    const float* out_proj_w= (const float*)d_in[9];
    float* out = (float*)d_out;

    // workspace layout (~80.7 MB, unchanged from r3); xbf aliases dt (xbf dead
    // after G1; dt zeroed after G1, then atomic-accumulated in G2).
    char* p = (char*)d_ws;
    float* dt   = (float*)p;                          p += (size_t)MM * DINNER * 4;       // 16.8 MB
    bf16*  xbf  = (bf16*)dt;
    bf16*  xz   = (bf16*)p;                           p += (size_t)MM * N_XZ * 2;         // 16.8 MB
    bf16*  u    = (bf16*)p;                           p += (size_t)MM * DINNER * 2;       // 8.4 MB
    bf16*  wft  = (bf16*)p;                           p += (size_t)MM * N_SSM * 2;        // slot 8.5 MB
    bf16*  Wt1  = (bf16*)p;                           p += (size_t)N_XZ * DMODEL * 2;     // 8.4 MB
    bf16*  w2slot = (bf16*)p;                         p += (size_t)N_SSM_PAD * DINNER * 2;// 8.9 MB
    bf16*  W2bf = w2slot;
    bf16*  w2bc = w2slot + (size_t)DINNER * N_SSM;    // 32x2048 slot tail
    bf16*  Wt3  = (bf16*)p;                           p += (size_t)DINNER * DINNER * 2;   // 8.4 MB
    bf16*  Wt4  = (bf16*)p;                           p += (size_t)DMODEL * DINNER * 2;   // 4.2 MB
    float* BC   = (float*)p;                          p += (size_t)MM * 32 * 4;           // 256 KB
    float* chunkP = (float*)Wt1;     // Wt1 dead after G1
    float* chunkH = (float*)w2slot;  // W2bf dead after G2

    // 0) prep: W1/W3/W4 transposes + W2 cvt + W2[:, :32] transpose + x cvt
    prep_kernel<<<16512, 256, 0, stream>>>(x, xbf, in_proj_w, Wt1, dt_proj_w, Wt3,
                                           out_proj_w, Wt4, x_proj_w, W2bf, w2bc);
    // 1) G1 dual (768 blocks; long-pole Wf first):
    //    sub0: Wf^T = W3t @ W2dt (2048x2048, K=2048) 256 blocks (16x16), SWZ=1
    //    sub1: xz = xbf @ W1t    (2048x4096, K=1024) 512 blocks (32x16), SWZ=2
    mfma_gemm_dual<0, 1, 1, 0, 1, 2><<<768, 256, 0, stream>>>(
        256, 16, Wt3, DINNER, W2bf + 32, N_SSM, nullptr, wft, DINNER, nullptr, DINNER, DINNER,
        32, xbf, DMODEL, Wt1, DMODEL, nullptr, xz, N_XZ, nullptr, N_XZ, DMODEL);
    // zero atomic accumulators (dt aliases xbf: free only after G1)
    hipMemsetAsync(dt, 0, (size_t)MM * DINNER * 4, stream);
    hipMemsetAsync(out, 0, (size_t)out_size * sizeof(float), stream);
    // 2) u = silu(conv(x_inner)+b)
    {
        int n = BB * LL * DINNER / 8;
        conv_silu_kernel<<<(n + 255) / 256, 256, 0, stream>>>(xz, conv_w, conv_b, u);
    }
    // 3) G2 dual (528 blocks; long-pole BC first):
    //    sub0: BC = u @ W2[:, :32]  (2048x32, K=2048)  16 blocks, EPI=3
    //    sub1: dt_raw = u @ Wf      (2048x2048, K=2048) 256 tiles x splitK2 = 512, EPI=2
    mfma_gemm_dual<3, 1, -1, 2, 2, 1><<<528, 256, 0, stream>>>(
        16, 1, u, DINNER, w2bc, DINNER, BC, nullptr, 32, nullptr, 32, DINNER,
        16, u, DINNER, wft, DINNER, dt, nullptr, DINNER, nullptr, DINNER, DINNER);
    // 4) chunked selective scan (softplus(dt_raw + bias) applied on read)
    scan_phase_a<<<dim3(DINNER / 256, CCH, BB), 256, 0, stream>>>(dt, u, BC, A_log, dt_proj_b, chunkP, chunkH);
    scan_phase_p<<<dim3(BB * DINNER * DSTATE / 256), 256, 0, stream>>>(chunkP, chunkH);
    scan_phase_b<<<dim3(DINNER / 256, CCH, BB), 256, 0, stream>>>(dt, u, BC, xz, A_log, Dp, dt_proj_b, chunkH);
    // 5) out = y @ W4 (2048x1024, K=2048), split-K=4 atomic — 512 blocks, SWZ=0
    mfma_gemm<2, 4, 0><<<dim3(8, 16, 4), 256, 0, stream>>>(
        u, DINNER, Wt4, DINNER, out, nullptr, DMODEL, nullptr, DMODEL, DINNER);
}

// Round 7
// 336.516 us; speedup vs baseline: 1.2042x; 1.1382x over previous
//
#include <hip/hip_runtime.h>
#include <hip/hip_bf16.h>

// Dims (fixed for this problem)
#define BB 2
#define LL 1024
#define DMODEL 1024
#define DINNER 2048
#define DSTATE 16
#define DCONV 4
#define MM (BB * LL)          // 2048
#define N_XZ 4096
#define N_SSM 2080
#define N_SSM_PAD 2176        // 34 * 64
#define CCH 32                // chunks over L
#define LCH 32                // chunk length (CCH*LCH == LL)

typedef __hip_bfloat16 bf16;
typedef short bf16x8 __attribute__((ext_vector_type(8)));
typedef float f32x4 __attribute__((ext_vector_type(4)));

// ---------------- async global -> LDS, 16B per lane ----------------
__device__ __forceinline__ void load16_lds(const bf16* g, bf16* l) {
    __builtin_amdgcn_global_load_lds(
        (const __attribute__((address_space(1))) void*)g,
        (__attribute__((address_space(3))) void*)l,
        16, 0, 0);
}

template<int SWZ>
__device__ __forceinline__ void remap(int id, int NX, int& bx, int& by) {
    if (SWZ >= 0) {   // bind XCD (id&7) to a contiguous 2^SWZ range of n-tiles
        int xcd = id & 7, slot = id >> 3;
        bx = (xcd << SWZ) + (slot & ((1 << SWZ) - 1));
        by = slot >> SWZ;
    } else { bx = id % NX; by = id / NX; }
}

// ---------------- fused prep: 3 weight transposes + W2 cvt + BC-slice transpose + x cvt
__global__ __launch_bounds__(256) void prep_kernel(
    const float* __restrict__ x, bf16* __restrict__ xbf,
    const float* __restrict__ w1, bf16* __restrict__ o1,
    const float* __restrict__ w3, bf16* __restrict__ o3,
    const float* __restrict__ w4, bf16* __restrict__ o4,
    const float* __restrict__ w2, bf16* __restrict__ w2bf,
    bf16* __restrict__ w2bc)
{
    int bid = blockIdx.x;
    if (bid >= 14464) {                 // x cvt: 2048 blocks x 1024 elems
        bid -= 14464;
        int i = (bid * 256 + threadIdx.x) * 4;
        float4 v = *(const float4*)(x + i);
        xbf[i + 0] = __float2bfloat16(v.x);
        xbf[i + 1] = __float2bfloat16(v.y);
        xbf[i + 2] = __float2bfloat16(v.z);
        xbf[i + 3] = __float2bfloat16(v.w);
        return;
    }
    if (bid >= 10240 && bid < 14400) {  // w2 cvt: 2048*2080 f32 -> bf16, 4160 blocks
        bid -= 10240;
        int i = (bid * 256 + threadIdx.x) * 4;
        float4 v = *(const float4*)(w2 + i);
        w2bf[i + 0] = __float2bfloat16(v.x);
        w2bf[i + 1] = __float2bfloat16(v.y);
        w2bf[i + 2] = __float2bfloat16(v.z);
        w2bf[i + 3] = __float2bfloat16(v.w);
        return;
    }
    const float* src; bf16* dst; int K, N, tn, tk, srcld;
    if (bid < 4096)        { src = w1; dst = o1; K = 1024; N = 4096; tn = bid & 127; tk = bid >> 7; srcld = N; }
    else if (bid < 8192)   { bid -= 4096; src = w3; dst = o3; K = 2048; N = 2048; tn = bid & 63; tk = bid >> 6; srcld = N; }
    else if (bid < 10240)  { bid -= 8192; src = w4; dst = o4; K = 2048; N = 1024; tn = bid & 31; tk = bid >> 5; srcld = N; }
    else                   { bid -= 14400; src = w2; dst = w2bc; K = 2048; N = 32; tn = 0; tk = bid; srcld = N_SSM; }
    __shared__ float tile[32][33];
    const int nb = tn * 32, kb = tk * 32;
    const int tx = threadIdx.x & 31, ty = threadIdx.x >> 5;
    #pragma unroll
    for (int i = 0; i < 32; i += 8) {
        int k = kb + ty + i, n = nb + tx;
        tile[ty + i][tx] = (k < K && n < N) ? src[(size_t)k * srcld + n] : 0.f;
    }
    __syncthreads();
    #pragma unroll
    for (int i = 0; i < 32; i += 8) {
        int n = nb + ty + i, k = kb + tx;
        if (n < N && k < K) dst[(size_t)n * K + k] = __float2bfloat16(tile[tx][ty + i]);
    }
}

// ================= BODY A: 128x128 tile, 4 waves x (64x64) — measured 573 TF ========
// (r6 G1: 60us for xz+Wf). v6 2-buf counted-vmcnt schedule + XOR chunk swizzle
// (SQ_LDS_BANK_CONFLICT==0 on HW). 8 loads/wave/stage -> vmcnt(8). 64 KB LDS.
__device__ __forceinline__ void gemm_body128(
    bf16* AsB, bf16* BsB, int bx, int by,
    const bf16* __restrict__ A, int lda,
    const bf16* __restrict__ Wt, int ldw,
    bf16* __restrict__ Cb, int ldc,
    int N, int K)
{
    const int tid = threadIdx.x;
    const int wave = tid >> 6, lane = tid & 63;
    const int wm = (wave >> 1) * 64, wn = (wave & 1) * 64;
    const int m0 = by * 128, n0 = bx * 128;
    const int lm = lane & 15, kq = lane >> 4;

    const int srow = lane >> 3;
    const int schunk = (lane & 7) ^ srow;
    const bf16* gA = A  + (size_t)(m0 + wave * 32 + srow) * lda + schunk * 8;
    const bf16* gB = Wt + (size_t)(n0 + wave * 32 + srow) * ldw + schunk * 8;

    const int NK = K / 64;    // even for all call sites
    f32x4 acc[4][4] = {};
    const int fsw = lm & 7;

    auto stage = [&](int buf, int it) {
        const int k0 = it * 64;
        bf16* lA = AsB + buf * (128 * 64) + (wave * 32) * 64;
        bf16* lB = BsB + buf * (128 * 64) + (wave * 32) * 64;
        #pragma unroll
        for (int g = 0; g < 4; ++g) {
            load16_lds(gA + (size_t)(8 * g) * lda + k0, lA + (8 * g) * 64);
            load16_lds(gB + (size_t)(8 * g) * ldw + k0, lB + (8 * g) * 64);
        }
    };
    auto compute = [&](int buf) {
        const bf16* Asb = AsB + buf * (128 * 64);
        const bf16* Bsb = BsB + buf * (128 * 64);
        bf16x8 af[4][2], bfr[4][2];
        #pragma unroll
        for (int i = 0; i < 4; ++i)
            #pragma unroll
            for (int t = 0; t < 2; ++t)
                af[i][t] = *(const bf16x8*)(&Asb[(wm + i * 16 + lm) * 64 + ((t * 4 + kq) ^ fsw) * 8]);
        #pragma unroll
        for (int j = 0; j < 4; ++j)
            #pragma unroll
            for (int t = 0; t < 2; ++t)
                bfr[j][t] = *(const bf16x8*)(&Bsb[(wn + j * 16 + lm) * 64 + ((t * 4 + kq) ^ fsw) * 8]);
        #pragma unroll
        for (int t = 0; t < 2; ++t)
            #pragma unroll
            for (int i = 0; i < 4; ++i)
                #pragma unroll
                for (int j = 0; j < 4; ++j)
                    acc[i][j] = __builtin_amdgcn_mfma_f32_16x16x32_bf16(af[i][t], bfr[j][t], acc[i][j], 0, 0, 0);
    };

    stage(0, 0);
    for (int it = 0; it < NK; it += 2) {
        stage(1, it + 1);
        __builtin_amdgcn_s_waitcnt(0x0F78);       // vmcnt(8)
        __builtin_amdgcn_s_barrier();
        compute(0);
        __builtin_amdgcn_s_barrier();
        if (it + 2 < NK) {
            stage(0, it + 2);
            __builtin_amdgcn_s_waitcnt(0x0F78);
        } else {
            __builtin_amdgcn_s_waitcnt(0x0F70);   // vmcnt(0)
        }
        __builtin_amdgcn_s_barrier();
        compute(1);
        __builtin_amdgcn_s_barrier();
    }

    // D layout: col = lane&15, row = (lane>>4)*4 + r (m89-verified)
    #pragma unroll
    for (int i = 0; i < 4; ++i) {
        #pragma unroll
        for (int j = 0; j < 4; ++j) {
            int gcol = n0 + wn + j * 16 + lm;
            if (gcol >= N) continue;
            #pragma unroll
            for (int r = 0; r < 4; ++r) {
                int grow = m0 + wm + i * 16 + kq * 4 + r;
                Cb[(size_t)grow * ldc + gcol] = __float2bfloat16(acc[i][j][r]);
            }
        }
    }
}

// G1 dual (128x128 body): Wf (256 tiles, long pole, SWZ=1) + xz (512 tiles, SWZ=2)
__global__ __launch_bounds__(256, 2) void mfma_dual128(
    int nblk0, int NX0,
    const bf16* __restrict__ A0, int lda0, const bf16* __restrict__ Wt0, int ldw0,
    bf16* __restrict__ Cb0, int ldc0, int N0, int K0,
    int NX1,
    const bf16* __restrict__ A1, int lda1, const bf16* __restrict__ Wt1, int ldw1,
    bf16* __restrict__ Cb1, int ldc1, int N1, int K1)
{
    __shared__ __align__(16) bf16 As[2 * 128 * 64];
    __shared__ __align__(16) bf16 Bs[2 * 128 * 64];
    int id = blockIdx.x;
    if (id < nblk0) {
        int bx, by; remap<1>(id, NX0, bx, by);
        gemm_body128(As, Bs, bx, by, A0, lda0, Wt0, ldw0, Cb0, ldc0, N0, K0);
    } else {
        int bx, by; remap<2>(id - nblk0, NX1, bx, by);
        gemm_body128(As, Bs, bx, by, A1, lda1, Wt1, ldw1, Cb1, ldc1, N1, K1);
    }
}

// ================= BODY B: 128x64 tile, 4 waves x (64x32) — r3-verified =============
// EPI: 0 = bf16 store (col<N guard), 1 = +bias softplus f32, 2 = f32 (atomic if at),
//      3 = cols<32 -> f32 sideband (ld 32), cols in [32,N) skipped via N guard
template<int EPI>
__device__ __forceinline__ void gemm_body64(
    bf16* AsB, bf16* BsB, int bx, int by,
    const bf16* __restrict__ A, int lda,
    const bf16* __restrict__ Wt, int ldw,
    float* __restrict__ Cf, bf16* __restrict__ Cb, int ldc,
    const float* __restrict__ bias,
    int N, int K, int kbeg, int Kc, bool at)
{
    const int tid = threadIdx.x;
    const int wave = tid >> 6, lane = tid & 63;
    const int wm = (wave >> 1) * 64, wn = (wave & 1) * 32;
    const int m0 = by * 128, n0 = bx * 64;
    const int lm = lane & 15, kq = lane >> 4;

    const int srow = lane >> 3;
    const int schunk = (lane & 7) ^ srow;
    const bf16* gA = A + (size_t)(m0 + wave * 32 + srow) * lda + schunk * 8;
    const bf16* gB = Wt + (size_t)(n0 + wave * 16 + srow) * ldw + schunk * 8;

    const int NK = Kc / 64;   // even
    f32x4 acc[4][2] = {};
    const int fsw = (lm & 7);

    auto stage = [&](int buf, int it) {
        const int k0 = kbeg + it * 64;
        bf16* lA = AsB + buf * (128 * 64) + (wave * 32) * 64;
        bf16* lB = BsB + buf * (64 * 64) + (wave * 16) * 64;
        #pragma unroll
        for (int g = 0; g < 4; ++g)
            load16_lds(gA + (size_t)(8 * g) * lda + k0, lA + (8 * g) * 64);
        #pragma unroll
        for (int g = 0; g < 2; ++g)
            load16_lds(gB + (size_t)(8 * g) * ldw + k0, lB + (8 * g) * 64);
    };
    auto compute = [&](int buf) {
        const bf16* Asb = AsB + buf * (128 * 64);
        const bf16* Bsb = BsB + buf * (64 * 64);
        bf16x8 af[4][2], bfr[2][2];
        #pragma unroll
        for (int i = 0; i < 4; ++i)
            #pragma unroll
            for (int t = 0; t < 2; ++t)
                af[i][t] = *(const bf16x8*)(&Asb[(wm + i * 16 + lm) * 64 + ((t * 4 + kq) ^ fsw) * 8]);
        #pragma unroll
        for (int j = 0; j < 2; ++j)
            #pragma unroll
            for (int t = 0; t < 2; ++t)
                bfr[j][t] = *(const bf16x8*)(&Bsb[(wn + j * 16 + lm) * 64 + ((t * 4 + kq) ^ fsw) * 8]);
        #pragma unroll
        for (int t = 0; t < 2; ++t)
            #pragma unroll
            for (int i = 0; i < 4; ++i)
                #pragma unroll
                for (int j = 0; j < 2; ++j)
                    acc[i][j] = __builtin_amdgcn_mfma_f32_16x16x32_bf16(af[i][t], bfr[j][t], acc[i][j], 0, 0, 0);
    };

    stage(0, 0);
    for (int it = 0; it < NK; it += 2) {
        stage(1, it + 1);
        __builtin_amdgcn_s_waitcnt(0x0F76);       // vmcnt(6)
        __builtin_amdgcn_s_barrier();
        compute(0);
        __builtin_amdgcn_s_barrier();
        if (it + 2 < NK) {
            stage(0, it + 2);
            __builtin_amdgcn_s_waitcnt(0x0F76);
        } else {
            __builtin_amdgcn_s_waitcnt(0x0F70);
        }
        __builtin_amdgcn_s_barrier();
        compute(1);
        __builtin_amdgcn_s_barrier();
    }

    #pragma unroll
    for (int i = 0; i < 4; ++i) {
        #pragma unroll
        for (int j = 0; j < 2; ++j) {
            int gcol = n0 + wn + j * 16 + lm;
            if ((EPI == 0 || EPI == 3) && gcol >= N) continue;
            #pragma unroll
            for (int r = 0; r < 4; ++r) {
                int grow = m0 + wm + i * 16 + kq * 4 + r;
                float v = acc[i][j][r];
                if (EPI == 1) {
                    v += bias[gcol];
                    v = (v > 20.f) ? v : log1pf(__expf(v));
                    Cf[(size_t)grow * ldc + gcol] = v;
                } else if (EPI == 2) {
                    if (at) atomicAdd(&Cf[(size_t)grow * ldc + gcol], v);
                    else    Cf[(size_t)grow * ldc + gcol] = v;
                } else if (EPI == 3) {
                    Cf[(size_t)grow * 32 + gcol] = v;     // f32 sideband (N<=32)
                } else {
                    Cb[(size_t)grow * ldc + gcol] = __float2bfloat16(v);
                }
            }
        }
    }
}

// single 64-wide GEMM (2D grid + optional split-K over z) — r3's out kernel
template<int EPI, int KSPLIT = 1, int SWZ = -1>
__global__ __launch_bounds__(256) void mfma_gemm64(
    const bf16* __restrict__ A, int lda,
    const bf16* __restrict__ Wt, int ldw,
    float* __restrict__ Cf, bf16* __restrict__ Cb, int ldc,
    const float* __restrict__ bias,
    int N, int K)
{
    __shared__ __align__(16) bf16 As[2 * 128 * 64];
    __shared__ __align__(16) bf16 Bs[2 * 64 * 64];
    int bx, by;
    if (SWZ >= 0) {
        int id = blockIdx.x + (int)(gridDim.x * blockIdx.y);
        remap<SWZ>(id, gridDim.x, bx, by);
    } else { bx = blockIdx.x; by = blockIdx.y; }
    const int Kc = K / KSPLIT;
    const int kbeg = (KSPLIT > 1) ? blockIdx.z * Kc : 0;
    gemm_body64<EPI>(As, Bs, bx, by, A, lda, Wt, ldw, Cf, Cb, ldc,
                     bias, N, K, kbeg, Kc, KSPLIT > 1);
}

// dual 64-wide GEMM — r3's megaB kernel
template<int EPI0, int SWZ0, int EPI1, int SWZ1>
__global__ __launch_bounds__(256) void mfma_dual64(
    int nblk0, int NX0,
    const bf16* __restrict__ A0, int lda0, const bf16* __restrict__ Wt0, int ldw0,
    float* __restrict__ Cf0, bf16* __restrict__ Cb0, int ldc0,
    const float* __restrict__ bias0, int N0, int K0,
    int NX1,
    const bf16* __restrict__ A1, int lda1, const bf16* __restrict__ Wt1, int ldw1,
    float* __restrict__ Cf1, bf16* __restrict__ Cb1, int ldc1,
    const float* __restrict__ bias1, int N1, int K1)
{
    __shared__ __align__(16) bf16 As[2 * 128 * 64];
    __shared__ __align__(16) bf16 Bs[2 * 64 * 64];
    int id = blockIdx.x;
    if (id < nblk0) {
        int bx, by; remap<SWZ0>(id, NX0, bx, by);
        gemm_body64<EPI0>(As, Bs, bx, by, A0, lda0, Wt0, ldw0,
                          Cf0, Cb0, ldc0, bias0, N0, K0, 0, K0, false);
    } else {
        id -= nblk0;
        int bx, by; remap<SWZ1>(id, NX1, bx, by);
        gemm_body64<EPI1>(As, Bs, bx, by, A1, lda1, Wt1, ldw1,
                          Cf1, Cb1, ldc1, bias1, N1, K1, 0, K1, false);
    }
}

// ---------------- depthwise causal conv (k=4) + bias + SiLU (bf16 io, 8 ch/thread) ----
__global__ void conv_silu_kernel(const bf16* __restrict__ xz,
                                 const float* __restrict__ conv_w,
                                 const float* __restrict__ conv_b,
                                 bf16* __restrict__ u)
{
    int idx = blockIdx.x * blockDim.x + threadIdx.x;   // over BB*LL*DINNER/8
    int d8 = idx & (DINNER / 8 - 1);
    int l  = (idx >> 8) & (LL - 1);
    int b  = idx >> 18;
    int d0 = d8 * 8;

    float acc[8];
    {
        float4 b0 = *(const float4*)(conv_b + d0);
        float4 b1 = *(const float4*)(conv_b + d0 + 4);
        acc[0] = b0.x; acc[1] = b0.y; acc[2] = b0.z; acc[3] = b0.w;
        acc[4] = b1.x; acc[5] = b1.y; acc[6] = b1.z; acc[7] = b1.w;
    }
    #pragma unroll
    for (int j = 0; j < DCONV; ++j) {
        int ll = l - (DCONV - 1) + j;
        if (ll >= 0) {
            bf16x8 v = *(const bf16x8*)(xz + ((size_t)(b * LL + ll)) * N_XZ + d0);
            #pragma unroll
            for (int r = 0; r < 8; ++r) {
                float xv = __uint_as_float(((unsigned)(unsigned short)v[r]) << 16);
                acc[r] = fmaf(conv_w[(d0 + r) * DCONV + j], xv, acc[r]);
            }
        }
    }
    bf16x8 out;
    #pragma unroll
    for (int r = 0; r < 8; ++r) {
        float y = acc[r] / (1.f + __expf(-acc[r]));
        bf16 h = __float2bfloat16(y);
        out[r] = *reinterpret_cast<short*>(&h);
    }
    *(bf16x8*)(u + ((size_t)(b * LL + l)) * DINNER + d0) = out;
}

// ---------------- scan phase A: lane per (b,d,chunk), h[16] in regs ----------------
__global__ __launch_bounds__(256) void scan_phase_a(
    const float* __restrict__ dt, const bf16* __restrict__ u,
    const float* __restrict__ BC,    // (B,L,32) f32: B=[0:16), C=[16:32)
    const float* __restrict__ A_log,
    float* __restrict__ chunkP, float* __restrict__ chunkH)
{
    const int d = blockIdx.x * 256 + threadIdx.x;
    const int c = blockIdx.y, b = blockIdx.z;
    const int l0 = c * LCH;

    float A[DSTATE];
    {
        const f32x4* ap = (const f32x4*)(A_log + d * DSTATE);
        #pragma unroll
        for (int q = 0; q < 4; ++q) {
            f32x4 v = ap[q];
            #pragma unroll
            for (int r = 0; r < 4; ++r) A[q * 4 + r] = -__expf(v[r]);
        }
    }
    float h[DSTATE];
    #pragma unroll
    for (int n = 0; n < DSTATE; ++n) h[n] = 0.f;
    float sdt = 0.f;

    const float* dtp = dt + ((size_t)b * LL + l0) * DINNER + d;
    const bf16* up = u + ((size_t)b * LL + l0) * DINNER + d;
    const float* bcp = BC + ((size_t)b * LL + l0) * 32;

    #pragma unroll 2
    for (int i = 0; i < LCH; ++i) {
        float dtv = *dtp;
        float uv  = (float)*up;
        float du  = dtv * uv;
        f32x4 Bv[4];
        #pragma unroll
        for (int q = 0; q < 4; ++q) Bv[q] = *(const f32x4*)(bcp + q * 4);
        #pragma unroll
        for (int n = 0; n < DSTATE; ++n) {
            float a = __expf(dtv * A[n]);
            h[n] = fmaf(a, h[n], du * Bv[n >> 2][n & 3]);
        }
        sdt += dtv;
        dtp += DINNER; up += DINNER; bcp += 32;
    }

    size_t idx = (((size_t)b * CCH + c) * DINNER + d) * DSTATE;
    #pragma unroll
    for (int q = 0; q < 4; ++q) {
        f32x4 pv, hv;
        #pragma unroll
        for (int r = 0; r < 4; ++r) { pv[r] = __expf(A[q * 4 + r] * sdt); hv[r] = h[q * 4 + r]; }
        *(f32x4*)(chunkP + idx + q * 4) = pv;
        *(f32x4*)(chunkH + idx + q * 4) = hv;
    }
}

// ---------------- scan phase P: exclusive prefix over chunks, in place on chunkH ----
__global__ __launch_bounds__(256) void scan_phase_p(
    const float* __restrict__ chunkP, float* __restrict__ chunkH)
{
    int gid = blockIdx.x * 256 + threadIdx.x;   // over B*DINNER*DSTATE = 65536
    int n = gid & 15;
    int d = (gid >> 4) & (DINNER - 1);
    int b = gid >> 15;
    const size_t stride = (size_t)DINNER * DSTATE;
    size_t idx = ((size_t)b * CCH * DINNER + d) * DSTATE + n;
    float H = 0.f;
    for (int c = 0; c < CCH; ++c) {
        float P  = chunkP[idx];
        float hl = chunkH[idx];
        chunkH[idx] = H;           // exclusive prefix
        H = fmaf(P, H, hl);
        idx += stride;
    }
}

// ---------------- scan phase B: lane per (b,d,chunk); gated y over u --------
__global__ __launch_bounds__(256) void scan_phase_b(
    const float* __restrict__ dt, bf16* __restrict__ u,
    const float* __restrict__ BC, const bf16* __restrict__ xz,
    const float* __restrict__ A_log, const float* __restrict__ Dp,
    const float* __restrict__ chunkH)
{
    const int d = blockIdx.x * 256 + threadIdx.x;
    const int c = blockIdx.y, b = blockIdx.z;
    const int l0 = c * LCH;

    float A[DSTATE];
    {
        const f32x4* ap = (const f32x4*)(A_log + d * DSTATE);
        #pragma unroll
        for (int q = 0; q < 4; ++q) {
            f32x4 v = ap[q];
            #pragma unroll
            for (int r = 0; r < 4; ++r) A[q * 4 + r] = -__expf(v[r]);
        }
    }
    const float Dd = Dp[d];
    float h[DSTATE];
    {
        size_t idx = (((size_t)b * CCH + c) * DINNER + d) * DSTATE;
        #pragma unroll
        for (int q = 0; q < 4; ++q) {
            f32x4 v = *(const f32x4*)(chunkH + idx + q * 4);
            #pragma unroll
            for (int r = 0; r < 4; ++r) h[q * 4 + r] = v[r];
        }
    }

    const float* dtp = dt + ((size_t)b * LL + l0) * DINNER + d;
    bf16* up = u + ((size_t)b * LL + l0) * DINNER + d;
    const float* bcp = BC + ((size_t)b * LL + l0) * 32;
    const bf16* zp = xz + ((size_t)b * LL + l0) * N_XZ + DINNER + d;

    #pragma unroll 2
    for (int i = 0; i < LCH; ++i) {
        float dtv = *dtp;
        float uv  = (float)*up;
        float du  = dtv * uv;
        f32x4 Bv[4], Cv[4];
        #pragma unroll
        for (int q = 0; q < 4; ++q) {
            Bv[q] = *(const f32x4*)(bcp + q * 4);
            Cv[q] = *(const f32x4*)(bcp + 16 + q * 4);
        }
        float acc = 0.f;
        #pragma unroll
        for (int n = 0; n < DSTATE; ++n) {
            float a = __expf(dtv * A[n]);
            h[n] = fmaf(a, h[n], du * Bv[n >> 2][n & 3]);
            acc = fmaf(h[n], Cv[n >> 2][n & 3], acc);
        }
        float zv = (float)*zp;
        acc = fmaf(Dd, uv, acc);
        acc *= zv / (1.f + __expf(-zv));
        *up = __float2bfloat16(acc);
        dtp += DINNER; up += DINNER; bcp += 32; zp += N_XZ;
    }
}

extern "C" void kernel_launch(void* const* d_in, const int* in_sizes, int n_in,
                              void* d_out, int out_size, void* d_ws, size_t ws_size,
                              hipStream_t stream) {
    const float* x         = (const float*)d_in[0];
    const float* in_proj_w = (const float*)d_in[1];
    const float* conv_w    = (const float*)d_in[2];
    const float* conv_b    = (const float*)d_in[3];
    const float* x_proj_w  = (const float*)d_in[4];
    const float* dt_proj_w = (const float*)d_in[5];
    const float* dt_proj_b = (const float*)d_in[6];
    const float* A_log     = (const float*)d_in[7];
    const float* Dp        = (const float*)d_in[8];
    const float* out_proj_w= (const float*)d_in[9];
    float* out = (float*)d_out;

    // workspace layout (~80.7 MB, identical to r3); xbf aliases dt (xbf dead after
    // G1; dt then written by megaB EPI=1). chunkP aliases Wt1; chunkH aliases w2slot.
    char* p = (char*)d_ws;
    float* dt   = (float*)p;                          p += (size_t)MM * DINNER * 4;       // 16.8 MB
    bf16*  xbf  = (bf16*)dt;
    bf16*  xz   = (bf16*)p;                           p += (size_t)MM * N_XZ * 2;         // 16.8 MB
    bf16*  u    = (bf16*)p;                           p += (size_t)MM * DINNER * 2;       // 8.4 MB
    bf16*  wft  = (bf16*)p;                           p += (size_t)MM * N_SSM * 2;        // slot 8.5 MB
    bf16*  Wt1  = (bf16*)p;                           p += (size_t)N_XZ * DMODEL * 2;     // 8.4 MB
    bf16*  w2slot = (bf16*)p;                         p += (size_t)N_SSM_PAD * DINNER * 2;// 8.9 MB
    bf16*  W2bf = w2slot;
    bf16*  w2bc = w2slot + (size_t)DINNER * N_SSM;    // 32x2048 slot tail (B-reads of
                                                      // rows 32..63 stay in-slot)
    bf16*  Wt3  = (bf16*)p;                           p += (size_t)DINNER * DINNER * 2;   // 8.4 MB
    bf16*  Wt4  = (bf16*)p;                           p += (size_t)DMODEL * DINNER * 2;   // 4.2 MB
    float* BC   = (float*)p;                          p += (size_t)MM * 32 * 4;           // 256 KB
    float* chunkP = (float*)Wt1;     // Wt1 dead after G1
    float* chunkH = (float*)w2slot;  // W2bf dead after megaB

    // 0) prep: W1/W3/W4 transposes + W2 cvt + W2[:, :32] transpose + x cvt
    prep_kernel<<<16512, 256, 0, stream>>>(x, xbf, in_proj_w, Wt1, dt_proj_w, Wt3,
                                           out_proj_w, Wt4, x_proj_w, W2bf, w2bc);
    // 1) G1 dual (768 blocks, 128x128 body — measured 60us):
    //    sub0: Wf^T = W3t @ W2dt (2048x2048, K=2048) 256 tiles (16x16), SWZ=1
    //    sub1: xz = xbf @ W1t    (2048x4096, K=1024) 512 tiles (32x16), SWZ=2
    mfma_dual128<<<768, 256, 0, stream>>>(
        256, 16, Wt3, DINNER, W2bf + 32, N_SSM, wft, DINNER, DINNER, DINNER,
        32, xbf, DMODEL, Wt1, DMODEL, xz, N_XZ, N_XZ, DMODEL);
    // 2) u = silu(conv(x_inner)+b)
    {
        int n = BB * LL * DINNER / 8;
        conv_silu_kernel<<<(n + 255) / 256, 256, 0, stream>>>(xz, conv_w, conv_b, u);
    }
    // 3) megaB (528 blocks, 64-wide body — r3-verified):
    //    sub0: dt = softplus(u @ Wf + b)  (2048x2048, K=2048) 512 blocks, EPI=1, SWZ=2
    //    sub1: BC = u @ W2[:, :32]        (2048x32,  K=2048)   16 blocks, EPI=3
    mfma_dual64<1, 2, 3, -1><<<528, 256, 0, stream>>>(
        512, 32, u, DINNER, wft, DINNER, dt, nullptr, DINNER, dt_proj_b, DINNER, DINNER,
        1, u, DINNER, w2bc, DINNER, BC, nullptr, 32, nullptr, 32, DINNER);
    // 4) chunked selective scan: A (local), P (prefix), B (apply; y over u)
    scan_phase_a<<<dim3(DINNER / 256, CCH, BB), 256, 0, stream>>>(dt, u, BC, A_log, chunkP, chunkH);
    scan_phase_p<<<dim3(BB * DINNER * DSTATE / 256), 256, 0, stream>>>(chunkP, chunkH);
    scan_phase_b<<<dim3(DINNER / 256, CCH, BB), 256, 0, stream>>>(dt, u, BC, xz, A_log, Dp, chunkH);
    // 5) out = y @ W4 (2048x1024, K=2048), split-K=4 atomic — 1024 blocks, SWZ=1 (r3 form)
    hipMemsetAsync(out, 0, (size_t)out_size * sizeof(float), stream);
    mfma_gemm64<2, 4, 1><<<dim3(16, 16, 4), 256, 0, stream>>>(
        u, DINNER, Wt4, DINNER, out, nullptr, DMODEL, nullptr, DMODEL, DINNER);
}